// Round 1
// baseline (431.218 us; speedup 1.0000x reference)
//
#include <hip/hip_runtime.h>
#include <math.h>

// Problem: B=64, T=4096, D=256
//   mids[b,d]   = sum_e W[d,e] * q[b,e]
//   scores[b,t] = tanh( sum_d k[b,t,d] * mids[b,d] + bias )
//   attn[b,t]   = softmax_t( scores ) with mask m applied to exp() terms
//
// Memory-bound on streaming k (256 MB fp32). Roofline floor ~42 us @ 6.3 TB/s.

#define BB 64
#define TT 4096
#define DD 256
#define TBLKS 32
#define ROWS_PER_BLOCK (TT / TBLKS)        // 128
#define ROWS_PER_WAVE  (ROWS_PER_BLOCK / 4) // 32

// ---------------- K1: mids = W @ q^T (per batch) ----------------
// One block per batch b, 4 waves; each wave computes 64 output d's.
// Per row: lane l holds W[d, 4l..4l+3] (float4, coalesced 1KB/wave-load),
// dot with q fragment, butterfly-reduce across 64 lanes.
__global__ __launch_bounds__(256) void mids_kernel(const float* __restrict__ q,
                                                   const float* __restrict__ W,
                                                   float* __restrict__ mids) {
    const int b    = blockIdx.x;
    const int lane = threadIdx.x & 63;
    const int wave = threadIdx.x >> 6;
    const float4 qf = ((const float4*)(q + (size_t)b * DD))[lane];
    for (int i = 0; i < 64; ++i) {
        const int d = wave * 64 + i;
        const float4 wf = ((const float4*)(W + (size_t)d * DD))[lane];
        float p = wf.x * qf.x + wf.y * qf.y + wf.z * qf.z + wf.w * qf.w;
        #pragma unroll
        for (int off = 32; off; off >>= 1) p += __shfl_xor(p, off, 64);
        if (lane == 0) mids[b * DD + d] = p;
    }
}

// ---------------- K2: scores = tanh(k . mids + bias), partial max ----------------
// grid (B, TBLKS), 256 threads = 4 waves. Each wave processes ROWS_PER_WAVE
// consecutive t rows; one float4/lane = exactly one 1KB row of k per load.
__global__ __launch_bounds__(256) void scores_kernel(const float* __restrict__ k,
                                                     const float* __restrict__ mids,
                                                     const float* __restrict__ bias,
                                                     float* __restrict__ scores,
                                                     float* __restrict__ partmax) {
    const int b    = blockIdx.x;
    const int tb   = blockIdx.y;
    const int lane = threadIdx.x & 63;
    const int wave = threadIdx.x >> 6;
    const float bv = bias[0];
    const float4 mf = ((const float4*)(mids + (size_t)b * DD))[lane];
    const float* kb = k + (size_t)b * TT * DD;

    __shared__ float wmax[4];
    float lmax = -2.0f;                       // tanh >= -1, safe sentinel
    const int t0 = tb * ROWS_PER_BLOCK + wave * ROWS_PER_WAVE;
    for (int i = 0; i < ROWS_PER_WAVE; ++i) {
        const int t = t0 + i;
        const float4 kf = ((const float4*)(kb + (size_t)t * DD))[lane];
        float p = kf.x * mf.x + kf.y * mf.y + kf.z * mf.z + kf.w * mf.w;
        #pragma unroll
        for (int off = 32; off; off >>= 1) p += __shfl_xor(p, off, 64);
        // p is now wave-uniform (butterfly); all lanes compute the same s
        const float s = tanhf(p + bv);
        if (lane == 0) scores[b * TT + t] = s;
        lmax = fmaxf(lmax, s);
    }
    if (lane == 0) wmax[wave] = lmax;
    __syncthreads();
    if (threadIdx.x == 0) {
        const float mm = fmaxf(fmaxf(wmax[0], wmax[1]), fmaxf(wmax[2], wmax[3]));
        partmax[b * TBLKS + tb] = mm;
    }
}

// ---------------- K3: masked softmax over t, per batch ----------------
// One block per batch. Reduce partial maxes, e = exp(s-max)*m -> out,
// block-reduce sum, normalize in place. Deterministic.
__global__ __launch_bounds__(256) void softmax_kernel(const float* __restrict__ scores,
                                                      const float* __restrict__ m,
                                                      const float* __restrict__ partmax,
                                                      float* __restrict__ out) {
    const int b    = blockIdx.x;
    const int tid  = threadIdx.x;
    const int lane = tid & 63;
    const int wave = tid >> 6;
    __shared__ float red[5];   // red[4] = max, red[0..3] = per-wave sums

    // --- max over TBLKS partials (wave 0 only) ---
    if (wave == 0) {
        float mv = (lane < TBLKS) ? partmax[b * TBLKS + lane] : -2.0f;
        #pragma unroll
        for (int off = 32; off; off >>= 1) mv = fmaxf(mv, __shfl_xor(mv, off, 64));
        if (lane == 0) red[4] = mv;
    }
    __syncthreads();
    const float maxv = red[4];

    // --- e = exp(s - max) * m; accumulate local sum ---
    float local = 0.0f;
    for (int t = tid; t < TT; t += 256) {
        const float e = expf(scores[b * TT + t] - maxv) * m[b * TT + t];
        out[b * TT + t] = e;
        local += e;
    }
    #pragma unroll
    for (int off = 32; off; off >>= 1) local += __shfl_xor(local, off, 64);
    if (lane == 0) red[wave] = local;
    __syncthreads();
    const float inv = 1.0f / (red[0] + red[1] + red[2] + red[3]);

    // --- normalize (same thread wrote these slots; no extra sync needed) ---
    for (int t = tid; t < TT; t += 256) out[b * TT + t] *= inv;
}

extern "C" void kernel_launch(void* const* d_in, const int* in_sizes, int n_in,
                              void* d_out, int out_size, void* d_ws, size_t ws_size,
                              hipStream_t stream) {
    const float* q    = (const float*)d_in[0];   // [B, D]
    const float* k    = (const float*)d_in[1];   // [B, T, D]
    const float* m    = (const float*)d_in[2];   // [B, T]
    const float* W    = (const float*)d_in[3];   // [D, D]
    const float* bias = (const float*)d_in[4];   // [1]
    float* out = (float*)d_out;                  // [B, T]

    float* ws      = (float*)d_ws;
    float* mids    = ws;                         // B*D     = 16384 floats
    float* scores  = mids + BB * DD;             // B*T     = 262144 floats
    float* partmax = scores + BB * TT;           // B*TBLKS = 2048 floats
    // total ws: ~1.07 MB

    mids_kernel<<<BB, 256, 0, stream>>>(q, W, mids);
    scores_kernel<<<dim3(BB, TBLKS), 256, 0, stream>>>(k, mids, bias, scores, partmax);
    softmax_kernel<<<BB, 256, 0, stream>>>(scores, m, partmax, out);
}

// Round 2
// 398.123 us; speedup vs baseline: 1.0831x; 1.0831x over previous
//
#include <hip/hip_runtime.h>
#include <math.h>

// Problem: B=64, T=4096, D=256
//   mids[b,d]   = sum_e W[d,e] * q[b,e]
//   scores[b,t] = tanh( sum_d k[b,t,d] * mids[b,d] + bias )
//   attn[b,t]   = softmax_t( scores ) with mask m applied to exp() terms
//
// Memory-bound on streaming k (256 MB fp32). Roofline floor ~42 us @ 6.3 TB/s.
// R1: 16-lane-group dot (4 rows/wave-group: 1 shfl/row, tanh amortized 4x),
//     fast tanh via v_exp+v_rcp, K1/K3 parallelized to full occupancy.

#define BB 64
#define TT 4096
#define DD 256
#define TBLKS 32
#define RPB (TT / TBLKS)     // 128 rows per block in scores kernel
#define GB 8                 // blocks per batch in softmax passes
#define CHUNK (TT / GB)      // 512

// tanh(x) = 1 - 2/(1 + e^{2x});  exact at +-inf (e=inf -> 1, e=0 -> -1)
__device__ __forceinline__ float fast_tanh(float x) {
    float e = __expf(2.0f * x);                       // v_exp_f32 path
    return 1.0f - 2.0f * __builtin_amdgcn_rcpf(1.0f + e);
}

// ---------------- K1: mids = W @ q^T ----------------
// grid (B, 4); block computes 64 d's. Wave handles 16 rows as 4 groups of 4:
// lane l -> row (l>>4), elements (l&15)*4 + j*64 (4 x float4 per lane).
__global__ __launch_bounds__(256) void mids_kernel(const float* __restrict__ q,
                                                   const float* __restrict__ W,
                                                   float* __restrict__ mids) {
    const int b    = blockIdx.x;
    const int seg  = blockIdx.y;
    const int lane = threadIdx.x & 63;
    const int wave = threadIdx.x >> 6;
    const int grp  = lane >> 4;
    const int l16  = lane & 15;

    const float* qb = q + (size_t)b * DD + l16 * 4;
    const float4 qf0 = *(const float4*)(qb + 0);
    const float4 qf1 = *(const float4*)(qb + 64);
    const float4 qf2 = *(const float4*)(qb + 128);
    const float4 qf3 = *(const float4*)(qb + 192);

    const int d0 = seg * 64 + wave * 16;
    #pragma unroll
    for (int g = 0; g < 4; ++g) {
        const int d = d0 + g * 4 + grp;
        const float* wr = W + (size_t)d * DD + l16 * 4;
        const float4 w0 = *(const float4*)(wr + 0);
        const float4 w1 = *(const float4*)(wr + 64);
        const float4 w2 = *(const float4*)(wr + 128);
        const float4 w3 = *(const float4*)(wr + 192);
        float p = w0.x*qf0.x + w0.y*qf0.y + w0.z*qf0.z + w0.w*qf0.w;
        p += w1.x*qf1.x + w1.y*qf1.y + w1.z*qf1.z + w1.w*qf1.w;
        p += w2.x*qf2.x + w2.y*qf2.y + w2.z*qf2.z + w2.w*qf2.w;
        p += w3.x*qf3.x + w3.y*qf3.y + w3.z*qf3.z + w3.w*qf3.w;
        p += __shfl_xor(p, 1, 64);
        p += __shfl_xor(p, 2, 64);
        p += __shfl_xor(p, 4, 64);
        p += __shfl_xor(p, 8, 64);
        if (l16 == 0) mids[b * DD + d] = p;
    }
}

// ---------------- K2: scores = tanh(k . mids + bias), partial max ----------------
// grid (B, TBLKS), 256 threads = 4 waves; wave handles 32 rows = 8 groups of 4.
__global__ __launch_bounds__(256) void scores_kernel(const float* __restrict__ k,
                                                     const float* __restrict__ mids,
                                                     const float* __restrict__ bias,
                                                     float* __restrict__ scores,
                                                     float* __restrict__ partmax) {
    const int b    = blockIdx.x;
    const int tb   = blockIdx.y;
    const int lane = threadIdx.x & 63;
    const int wave = threadIdx.x >> 6;
    const int grp  = lane >> 4;
    const int l16  = lane & 15;
    const float bv = bias[0];

    const float* mb = mids + (size_t)b * DD + l16 * 4;
    const float4 mf0 = *(const float4*)(mb + 0);
    const float4 mf1 = *(const float4*)(mb + 64);
    const float4 mf2 = *(const float4*)(mb + 128);
    const float4 mf3 = *(const float4*)(mb + 192);

    const int t0 = tb * RPB + wave * 32;
    const float* kbase = k + ((size_t)b * TT + t0) * DD + l16 * 4;

    float lmax = -2.0f;   // tanh >= -1
    #pragma unroll 2
    for (int g = 0; g < 8; ++g) {
        const int trow = g * 4 + grp;
        const float* kr = kbase + (size_t)trow * DD;
        const float4 k0 = *(const float4*)(kr + 0);
        const float4 k1 = *(const float4*)(kr + 64);
        const float4 k2 = *(const float4*)(kr + 128);
        const float4 k3 = *(const float4*)(kr + 192);
        float p = k0.x*mf0.x + k0.y*mf0.y + k0.z*mf0.z + k0.w*mf0.w;
        p += k1.x*mf1.x + k1.y*mf1.y + k1.z*mf1.z + k1.w*mf1.w;
        p += k2.x*mf2.x + k2.y*mf2.y + k2.z*mf2.z + k2.w*mf2.w;
        p += k3.x*mf3.x + k3.y*mf3.y + k3.z*mf3.z + k3.w*mf3.w;
        p += __shfl_xor(p, 1, 64);
        p += __shfl_xor(p, 2, 64);
        p += __shfl_xor(p, 4, 64);
        p += __shfl_xor(p, 8, 64);
        const float s = fast_tanh(p + bv);
        lmax = fmaxf(lmax, s);
        if (l16 == 0) scores[b * TT + t0 + trow] = s;   // 4 consecutive floats
    }
    // fold cross-group, then cross-wave max
    lmax = fmaxf(lmax, __shfl_xor(lmax, 16, 64));
    lmax = fmaxf(lmax, __shfl_xor(lmax, 32, 64));
    __shared__ float wmax[4];
    if (lane == 0) wmax[wave] = lmax;
    __syncthreads();
    if (threadIdx.x == 0)
        partmax[b * TBLKS + tb] =
            fmaxf(fmaxf(wmax[0], wmax[1]), fmaxf(wmax[2], wmax[3]));
}

// ---------------- K3a: e = exp(s - max) * m -> out, partial sums ----------------
// grid (B, GB), 256 threads; each thread handles 2 consecutive t's (float2).
__global__ __launch_bounds__(256) void exp_kernel(const float* __restrict__ scores,
                                                  const float* __restrict__ m,
                                                  const float* __restrict__ partmax,
                                                  float* __restrict__ out,
                                                  float* __restrict__ blocksum) {
    const int b    = blockIdx.x;
    const int g    = blockIdx.y;
    const int tid  = threadIdx.x;
    const int lane = tid & 63;
    const int wave = tid >> 6;
    __shared__ float smax;
    __shared__ float wsum[4];

    if (wave == 0) {
        float mv = (lane < TBLKS) ? partmax[b * TBLKS + lane] : -2.0f;
        #pragma unroll
        for (int off = 16; off; off >>= 1) mv = fmaxf(mv, __shfl_xor(mv, off, 64));
        if (lane == 0) smax = mv;
    }
    __syncthreads();
    const float maxv = smax;

    const int idx = b * TT + g * CHUNK + tid * 2;
    const float2 sv = *(const float2*)(scores + idx);
    const float2 mv2 = *(const float2*)(m + idx);
    const float e0 = __expf(sv.x - maxv) * mv2.x;
    const float e1 = __expf(sv.y - maxv) * mv2.y;
    *(float2*)(out + idx) = make_float2(e0, e1);

    float local = e0 + e1;
    #pragma unroll
    for (int off = 32; off; off >>= 1) local += __shfl_xor(local, off, 64);
    if (lane == 0) wsum[wave] = local;
    __syncthreads();
    if (tid == 0)
        blocksum[b * GB + g] = wsum[0] + wsum[1] + wsum[2] + wsum[3];
}

// ---------------- K3b: normalize ----------------
__global__ __launch_bounds__(256) void norm_kernel(const float* __restrict__ blocksum,
                                                   float* __restrict__ out) {
    const int b   = blockIdx.x;
    const int g   = blockIdx.y;
    const int tid = threadIdx.x;
    float s = 0.0f;
    #pragma unroll
    for (int i = 0; i < GB; ++i) s += blocksum[b * GB + i];
    const float inv = 1.0f / s;   // precise; one per thread
    const int idx = b * TT + g * CHUNK + tid * 2;
    float2 v = *(const float2*)(out + idx);
    v.x *= inv; v.y *= inv;
    *(float2*)(out + idx) = v;
}

extern "C" void kernel_launch(void* const* d_in, const int* in_sizes, int n_in,
                              void* d_out, int out_size, void* d_ws, size_t ws_size,
                              hipStream_t stream) {
    const float* q    = (const float*)d_in[0];   // [B, D]
    const float* k    = (const float*)d_in[1];   // [B, T, D]
    const float* m    = (const float*)d_in[2];   // [B, T]
    const float* W    = (const float*)d_in[3];   // [D, D]
    const float* bias = (const float*)d_in[4];   // [1]
    float* out = (float*)d_out;                  // [B, T]

    float* ws       = (float*)d_ws;
    float* mids     = ws;                        // B*D     = 16384 floats
    float* scores   = mids + BB * DD;            // B*T     = 262144 floats
    float* partmax  = scores + BB * TT;          // B*TBLKS = 2048 floats
    float* blocksum = partmax + BB * TBLKS;      // B*GB    = 512 floats

    mids_kernel<<<dim3(BB, 4), 256, 0, stream>>>(q, W, mids);
    scores_kernel<<<dim3(BB, TBLKS), 256, 0, stream>>>(k, mids, bias, scores, partmax);
    exp_kernel<<<dim3(BB, GB), 256, 0, stream>>>(scores, m, partmax, out, blocksum);
    norm_kernel<<<dim3(BB, GB), 256, 0, stream>>>(blocksum, out);
}

// Round 3
// 395.491 us; speedup vs baseline: 1.0903x; 1.0067x over previous
//
#include <hip/hip_runtime.h>
#include <math.h>

// Problem: B=64, T=4096, D=256
//   mids[b,d] = sum_e W[d,e] q[b,e]
//   attn[b,t] = softmax_t( tanh(k[b,t,:].mids[b,:] + bias) ) with mask m
//               applied to the exp() terms.
//
// KEY SIMPLIFICATION: tanh output is in (-1,1), so exp() cannot overflow and
// the max-stabilization term cancels exactly in e/sum(e). We therefore fuse
// scores+exp+mask into the single k-streaming pass (256 MB fp32, HBM-bound,
// roofline ~42 us @ 6.3 TB/s) and drop the scores/partmax round-trips.
//
// R3: DPP 16-lane sum tree (no ds_swizzle latency), explicit double-buffered
//     group loads so the wave always has memory in flight across the
//     tanh/exp dependent tail.

#define BB 64
#define TT 4096
#define DD 256
#define TBLKS 32
#define RPB (TT / TBLKS)     // 128 rows per scores-block
#define GB 8                 // blocks per batch in normalize pass
#define CHUNK (TT / GB)      // 512

// ---- 16-lane (DPP "row") full sum tree: every lane ends with the row sum ----
template<int CTRL>
__device__ __forceinline__ float dpp_add(float x) {
    int xi = __builtin_bit_cast(int, x);
    int yi = __builtin_amdgcn_update_dpp(0, xi, CTRL, 0xF, 0xF, true);
    return x + __builtin_bit_cast(float, yi);
}
__device__ __forceinline__ float row16_sum(float p) {
    p = dpp_add<0xB1>(p);    // quad_perm(1,0,3,2)  = xor 1
    p = dpp_add<0x4E>(p);    // quad_perm(2,3,0,1)  = xor 2
    p = dpp_add<0x141>(p);   // row_half_mirror     = pairs quads within 8
    p = dpp_add<0x140>(p);   // row_mirror          = pairs halves within 16
    return p;
}

// tanh(x) = 1 - 2/(1 + e^{2x}); exact at +-inf.
__device__ __forceinline__ float fast_tanh(float x) {
    float e = __expf(2.0f * x);
    return 1.0f - 2.0f * __builtin_amdgcn_rcpf(1.0f + e);
}

// ---------------- K1: mids = W @ q^T ----------------
// grid (B, 16); block = 256 thr = 4 waves; each 16-lane group computes one d.
__global__ __launch_bounds__(256) void mids_kernel(const float* __restrict__ q,
                                                   const float* __restrict__ W,
                                                   float* __restrict__ mids) {
    const int b    = blockIdx.x;
    const int seg  = blockIdx.y;
    const int lane = threadIdx.x & 63;
    const int wave = threadIdx.x >> 6;
    const int grp  = lane >> 4;
    const int l16  = lane & 15;

    const float* qb = q + (size_t)b * DD + l16 * 4;
    const float4 qf0 = *(const float4*)(qb + 0);
    const float4 qf1 = *(const float4*)(qb + 64);
    const float4 qf2 = *(const float4*)(qb + 128);
    const float4 qf3 = *(const float4*)(qb + 192);

    const int d = seg * 16 + wave * 4 + grp;
    const float* wr = W + (size_t)d * DD + l16 * 4;
    const float4 w0 = *(const float4*)(wr + 0);
    const float4 w1 = *(const float4*)(wr + 64);
    const float4 w2 = *(const float4*)(wr + 128);
    const float4 w3 = *(const float4*)(wr + 192);
    float p = w0.x*qf0.x + w0.y*qf0.y + w0.z*qf0.z + w0.w*qf0.w;
    p += w1.x*qf1.x + w1.y*qf1.y + w1.z*qf1.z + w1.w*qf1.w;
    p += w2.x*qf2.x + w2.y*qf2.y + w2.z*qf2.z + w2.w*qf2.w;
    p += w3.x*qf3.x + w3.y*qf3.y + w3.z*qf3.z + w3.w*qf3.w;
    p = row16_sum(p);
    if (l16 == 0) mids[b * DD + d] = p;
}

// ---------------- K2: e = exp(tanh(k.mids + bias)) * m -> out, block sums ----
// grid (B, TBLKS), 4 waves; wave handles 32 rows as 8 groups of 4 rows.
// Double-buffered loads: next group's 4 float4s issue before current compute.
__global__ __launch_bounds__(256) void fused_kernel(const float* __restrict__ k,
                                                    const float* __restrict__ mids,
                                                    const float* __restrict__ m,
                                                    const float* __restrict__ bias,
                                                    float* __restrict__ out,
                                                    float* __restrict__ blocksum) {
    const int b    = blockIdx.x;
    const int tb   = blockIdx.y;
    const int lane = threadIdx.x & 63;
    const int wave = threadIdx.x >> 6;
    const int grp  = lane >> 4;
    const int l16  = lane & 15;
    const float bv = bias[0];

    const float* mb = mids + (size_t)b * DD + l16 * 4;
    const float4 mf0 = *(const float4*)(mb + 0);
    const float4 mf1 = *(const float4*)(mb + 64);
    const float4 mf2 = *(const float4*)(mb + 128);
    const float4 mf3 = *(const float4*)(mb + 192);

    const int t0 = tb * RPB + wave * 32;              // 32 rows for this wave
    const float* kbase = k + ((size_t)b * TT + t0) * DD + l16 * 4;
    const float* mrow  = m + (size_t)b * TT + t0;
    float* orow        = out + (size_t)b * TT + t0;

    float4 c0, c1, c2, c3, n0, n1, n2, n3;
    {   // prologue: group 0 (rows grp+0..3)
        const float* kr = kbase + (size_t)grp * DD;
        c0 = *(const float4*)(kr + 0);
        c1 = *(const float4*)(kr + 64);
        c2 = *(const float4*)(kr + 128);
        c3 = *(const float4*)(kr + 192);
    }
    float esum = 0.0f;
    #pragma unroll
    for (int g = 0; g < 8; ++g) {
        if (g < 7) {  // issue next group's loads first
            const float* kr = kbase + (size_t)((g + 1) * 4 + grp) * DD;
            n0 = *(const float4*)(kr + 0);
            n1 = *(const float4*)(kr + 64);
            n2 = *(const float4*)(kr + 128);
            n3 = *(const float4*)(kr + 192);
        }
        float p = c0.x*mf0.x + c0.y*mf0.y + c0.z*mf0.z + c0.w*mf0.w;
        p += c1.x*mf1.x + c1.y*mf1.y + c1.z*mf1.z + c1.w*mf1.w;
        p += c2.x*mf2.x + c2.y*mf2.y + c2.z*mf2.z + c2.w*mf2.w;
        p += c3.x*mf3.x + c3.y*mf3.y + c3.z*mf3.z + c3.w*mf3.w;
        p = row16_sum(p);                              // group-uniform
        const float s = fast_tanh(p + bv);
        if (l16 == 0) {                                // lanes 0,16,32,48
            const int trow = g * 4 + grp;              // 4 consecutive t's
            const float e = __expf(s) * mrow[trow];
            orow[trow] = e;
            esum += e;
        }
        c0 = n0; c1 = n1; c2 = n2; c3 = n3;
    }
    // esum valid on lanes 0,16,32,48 (others are 0): fold to lane 0
    esum += __shfl_xor(esum, 16, 64);
    esum += __shfl_xor(esum, 32, 64);
    __shared__ float wsum[4];
    if (lane == 0) wsum[wave] = esum;
    __syncthreads();
    if (threadIdx.x == 0)
        blocksum[b * TBLKS + tb] = (wsum[0] + wsum[1]) + (wsum[2] + wsum[3]);
}

// ---------------- K3: normalize out by 1/sum ----------------
__global__ __launch_bounds__(256) void norm_kernel(const float* __restrict__ blocksum,
                                                   float* __restrict__ out) {
    const int b   = blockIdx.x;
    const int g   = blockIdx.y;
    const int tid = threadIdx.x;
    float s = 0.0f;
    #pragma unroll
    for (int i = 0; i < TBLKS; ++i) s += blocksum[b * TBLKS + i];  // uniform -> s_loads
    const float inv = 1.0f / s;
    const int idx = b * TT + g * CHUNK + tid * 2;
    float2 v = *(const float2*)(out + idx);
    v.x *= inv; v.y *= inv;
    *(float2*)(out + idx) = v;
}

extern "C" void kernel_launch(void* const* d_in, const int* in_sizes, int n_in,
                              void* d_out, int out_size, void* d_ws, size_t ws_size,
                              hipStream_t stream) {
    const float* q    = (const float*)d_in[0];   // [B, D]
    const float* k    = (const float*)d_in[1];   // [B, T, D]
    const float* m    = (const float*)d_in[2];   // [B, T]
    const float* W    = (const float*)d_in[3];   // [D, D]
    const float* bias = (const float*)d_in[4];   // [1]
    float* out = (float*)d_out;                  // [B, T]

    float* ws       = (float*)d_ws;
    float* mids     = ws;                        // B*D     = 16384 floats
    float* blocksum = mids + BB * DD;            // B*TBLKS = 2048 floats

    mids_kernel<<<dim3(BB, 16), 256, 0, stream>>>(q, W, mids);
    fused_kernel<<<dim3(BB, TBLKS), 256, 0, stream>>>(k, mids, m, bias, out, blocksum);
    norm_kernel<<<dim3(BB, GB), 256, 0, stream>>>(blocksum, out);
}

// Round 4
// 371.931 us; speedup vs baseline: 1.1594x; 1.0633x over previous
//
#include <hip/hip_runtime.h>
#include <math.h>

// Problem: B=64, T=4096, D=256
//   mids[b,d] = sum_e W[d,e] q[b,e]
//   attn[b,t] = softmax_t( tanh(k[b,t,:].mids[b,:] + bias) ), mask m applied
//               to the exp() terms.
//
// tanh in (-1,1) => exp can't overflow => max-stabilization cancels exactly.
// k streaming (256 MB fp32) is the whole cost; roofline ~41 us @ 6.3 TB/s.
//
// R4: latency fix. Register-dbuf only kept 256 B/wave in flight (~6 KB/CU vs
// the ~9.2 KB = BW x latency needed) and the per-row m-load serialized each
// iteration. Now: k staged via global_load_lds width=16 (fire-and-forget DMA,
// huge in-flight), 16-row chunks double-buffered in LDS (32 KB -> 5
// blocks/CU de-phase across barriers), mask m moved out of the hot loop into
// a cheap 2 MB post-pass.

#define BB 64
#define TT 4096
#define DD 256
#define TBLKS 32
#define RPB 128               // rows per block (t-dim)
#define CROWS 16              // rows per LDS chunk (16 KB)
#define NCH (RPB / CROWS)     // 8 chunks
#define GB 8
#define CHUNK (TT / GB)       // 512

// ---- DPP 16-lane full sum tree (all lanes end with the group sum) ----
template<int CTRL>
__device__ __forceinline__ float dpp_add(float x) {
    int xi = __builtin_bit_cast(int, x);
    int yi = __builtin_amdgcn_update_dpp(0, xi, CTRL, 0xF, 0xF, true);
    return x + __builtin_bit_cast(float, yi);
}
__device__ __forceinline__ float row16_sum(float p) {
    p = dpp_add<0xB1>(p);     // xor 1
    p = dpp_add<0x4E>(p);     // xor 2
    p = dpp_add<0x141>(p);    // row_half_mirror
    p = dpp_add<0x140>(p);    // row_mirror
    return p;
}

// tanh(x) = 1 - 2/(1 + e^{2x}); exact at +-inf.
__device__ __forceinline__ float fast_tanh(float x) {
    float e = __expf(2.0f * x);
    return 1.0f - 2.0f * __builtin_amdgcn_rcpf(1.0f + e);
}

// async global->LDS: one instruction moves 64 lanes x 16 B = one 1 KB row.
// LDS dest is wave-uniform base + lane*16 (hardware scatter).
__device__ __forceinline__ void async_row1k(const float* g, float* lds) {
    __builtin_amdgcn_global_load_lds(
        (const __attribute__((address_space(1))) void*)g,
        (__attribute__((address_space(3))) void*)lds,
        16, 0, 0);
}

// ---------------- K1: mids = W @ q^T ----------------
// grid (B, 16); 4 waves; each 16-lane group computes one d.
__global__ __launch_bounds__(256) void mids_kernel(const float* __restrict__ q,
                                                   const float* __restrict__ W,
                                                   float* __restrict__ mids) {
    const int b    = blockIdx.x;
    const int seg  = blockIdx.y;
    const int lane = threadIdx.x & 63;
    const int wave = threadIdx.x >> 6;
    const int grp  = lane >> 4;
    const int l16  = lane & 15;

    const float* qb = q + (size_t)b * DD + l16 * 4;
    const float4 qf0 = *(const float4*)(qb + 0);
    const float4 qf1 = *(const float4*)(qb + 64);
    const float4 qf2 = *(const float4*)(qb + 128);
    const float4 qf3 = *(const float4*)(qb + 192);

    const int d = seg * 16 + wave * 4 + grp;
    const float* wr = W + (size_t)d * DD + l16 * 4;
    const float4 w0 = *(const float4*)(wr + 0);
    const float4 w1 = *(const float4*)(wr + 64);
    const float4 w2 = *(const float4*)(wr + 128);
    const float4 w3 = *(const float4*)(wr + 192);
    float p = w0.x*qf0.x + w0.y*qf0.y + w0.z*qf0.z + w0.w*qf0.w;
    p += w1.x*qf1.x + w1.y*qf1.y + w1.z*qf1.z + w1.w*qf1.w;
    p += w2.x*qf2.x + w2.y*qf2.y + w2.z*qf2.z + w2.w*qf2.w;
    p += w3.x*qf3.x + w3.y*qf3.y + w3.z*qf3.z + w3.w*qf3.w;
    p = row16_sum(p);
    if (l16 == 0) mids[b * DD + d] = p;
}

// ---------------- K2: out[b,t] = exp(tanh(k.mids + bias)) ----------------
// grid (B, TBLKS); block streams 128 rows (128 KB) of k through LDS in
// 16-row chunks, double-buffered. Wave w stages rows w*4..w*4+3 of each
// chunk; 16-lane group g computes row g of the chunk.
__global__ __launch_bounds__(256) void stream_kernel(const float* __restrict__ k,
                                                     const float* __restrict__ mids,
                                                     const float* __restrict__ bias,
                                                     float* __restrict__ out) {
    __shared__ float buf[2][CROWS * DD];   // 2 x 16 KB
    const int b     = blockIdx.x;
    const int tb    = blockIdx.y;
    const int tid   = threadIdx.x;
    const int lane  = tid & 63;
    const int wave  = tid >> 6;
    const int l16   = lane & 15;
    const int grp16 = tid >> 4;            // 0..15: my row within the chunk
    const float bv  = bias[0];

    const float* mb = mids + (size_t)b * DD + l16 * 4;
    const float4 mf0 = *(const float4*)(mb + 0);
    const float4 mf1 = *(const float4*)(mb + 64);
    const float4 mf2 = *(const float4*)(mb + 128);
    const float4 mf3 = *(const float4*)(mb + 192);

    const int t0 = tb * RPB;
    const float* kb = k + ((size_t)b * TT + t0) * DD;
    float* orow = out + (size_t)b * TT + t0;

    // prologue: stage chunk 0
    {
        const float* src = kb + (size_t)(wave * 4) * DD + lane * 4;
        float* dst = &buf[0][(wave * 4) * DD];
        #pragma unroll
        for (int j = 0; j < 4; ++j) async_row1k(src + j * DD, dst + j * DD);
    }

    for (int c = 0; c < NCH; ++c) {
        if (c + 1 < NCH) {   // stage next chunk into the other buffer
            const float* src = kb + (size_t)((c + 1) * CROWS + wave * 4) * DD + lane * 4;
            float* dst = &buf[(c + 1) & 1][(wave * 4) * DD];
            #pragma unroll
            for (int j = 0; j < 4; ++j) async_row1k(src + j * DD, dst + j * DD);
        }
        __syncthreads();     // vmcnt drain + barrier: chunk c visible

        const float* row = &buf[c & 1][grp16 * DD + l16 * 4];
        const float4 r0 = *(const float4*)(row + 0);
        const float4 r1 = *(const float4*)(row + 64);
        const float4 r2 = *(const float4*)(row + 128);
        const float4 r3 = *(const float4*)(row + 192);
        float p = r0.x*mf0.x + r0.y*mf0.y + r0.z*mf0.z + r0.w*mf0.w;
        p += r1.x*mf1.x + r1.y*mf1.y + r1.z*mf1.z + r1.w*mf1.w;
        p += r2.x*mf2.x + r2.y*mf2.y + r2.z*mf2.z + r2.w*mf2.w;
        p += r3.x*mf3.x + r3.y*mf3.y + r3.z*mf3.z + r3.w*mf3.w;
        p = row16_sum(p);                      // group-uniform dot
        const float e = __expf(fast_tanh(p + bv));
        if (l16 == 0) orow[c * CROWS + grp16] = e;

        __syncthreads();     // protect buf[c&1] before it is restaged
    }
}

// ---------------- K3a: partial sums of out*m ----------------
__global__ __launch_bounds__(256) void sum_kernel(const float* __restrict__ out,
                                                  const float* __restrict__ m,
                                                  float* __restrict__ bsum) {
    const int b    = blockIdx.x;
    const int g    = blockIdx.y;
    const int tid  = threadIdx.x;
    const int lane = tid & 63;
    const int wave = tid >> 6;
    __shared__ float wsum[4];

    const int idx = b * TT + g * CHUNK + tid * 2;
    const float2 ov = *(const float2*)(out + idx);
    const float2 mv = *(const float2*)(m + idx);
    float local = ov.x * mv.x + ov.y * mv.y;
    #pragma unroll
    for (int off = 32; off; off >>= 1) local += __shfl_xor(local, off, 64);
    if (lane == 0) wsum[wave] = local;
    __syncthreads();
    if (tid == 0) bsum[b * GB + g] = (wsum[0] + wsum[1]) + (wsum[2] + wsum[3]);
}

// ---------------- K3b: out = out * m / sum ----------------
__global__ __launch_bounds__(256) void finish_kernel(const float* __restrict__ m,
                                                     const float* __restrict__ bsum,
                                                     float* __restrict__ out) {
    const int b   = blockIdx.x;
    const int g   = blockIdx.y;
    const int tid = threadIdx.x;
    float s = 0.0f;
    #pragma unroll
    for (int i = 0; i < GB; ++i) s += bsum[b * GB + i];   // uniform scalar loads
    const float inv = 1.0f / s;
    const int idx = b * TT + g * CHUNK + tid * 2;
    float2 v = *(const float2*)(out + idx);
    const float2 mv = *(const float2*)(m + idx);
    v.x *= mv.x * inv; v.y *= mv.y * inv;
    *(float2*)(out + idx) = v;
}

extern "C" void kernel_launch(void* const* d_in, const int* in_sizes, int n_in,
                              void* d_out, int out_size, void* d_ws, size_t ws_size,
                              hipStream_t stream) {
    const float* q    = (const float*)d_in[0];   // [B, D]
    const float* k    = (const float*)d_in[1];   // [B, T, D]
    const float* m    = (const float*)d_in[2];   // [B, T]
    const float* W    = (const float*)d_in[3];   // [D, D]
    const float* bias = (const float*)d_in[4];   // [1]
    float* out = (float*)d_out;                  // [B, T]

    float* ws   = (float*)d_ws;
    float* mids = ws;                            // B*D  = 16384 floats
    float* bsum = mids + BB * DD;                // B*GB = 512 floats

    mids_kernel<<<dim3(BB, 16), 256, 0, stream>>>(q, W, mids);
    stream_kernel<<<dim3(BB, TBLKS), 256, 0, stream>>>(k, mids, bias, out);
    sum_kernel<<<dim3(BB, GB), 256, 0, stream>>>(out, m, bsum);
    finish_kernel<<<dim3(BB, GB), 256, 0, stream>>>(m, bsum, out);
}